// Round 13
// baseline (504.160 us; speedup 1.0000x reference)
//
#include <hip/hip_runtime.h>
#include <hip/hip_bf16.h>
#include <math.h>

#define N_NODES 100000
#define N_EDGES 1600000
#define IN_F 256
#define HID 32
#define OUTC 16
#define NBUCK 1000
#define BUCK_W 100     // NBUCK * BUCK_W == N_NODES
#define NBB 256        // partition blocks
#define CHUNK 6250     // N_EDGES / NBB
#define MAXE 4096      // per-chunk edge capacity in LDS

typedef unsigned short ushort_t;
typedef unsigned int uint_t;

__device__ inline ushort_t f2bf(float f) {
    union { float f; uint_t u; } v; v.f = f;
    uint_t r = v.u + 0x7fff + ((v.u >> 16) & 1);   // round-to-nearest-even
    return (ushort_t)(r >> 16);
}
__device__ inline float bf2f(ushort_t h) {
    union { uint_t u; float f; } v; v.u = (uint_t)h << 16;
    return v.f;
}
__device__ inline float bf_lo(uint_t d) {
    union { uint_t u; float f; } v; v.u = d << 16;
    return v.f;
}
__device__ inline float bf_hi(uint_t d) {
    union { uint_t u; float f; } v; v.u = d & 0xFFFF0000u;
    return v.f;
}

// ============ Pass 1: per-block bucket histogram (LDS only) ============
__global__ __launch_bounds__(256) void k_cnt(const int* __restrict__ ei, int* __restrict__ bhist)
{
    __shared__ int lh[NBUCK];
    const int t = threadIdx.x;
    const int blk = blockIdx.x;
    for (int b = t; b < NBUCK; b += 256) lh[b] = 0;
    __syncthreads();
    const int base = blk * CHUNK;
    for (int i = t; i < CHUNK; i += 256) {
        const int dst = ei[N_EDGES + base + i];
        atomicAdd(&lh[dst / BUCK_W], 1);
    }
    __syncthreads();
    for (int b = t; b < NBUCK; b += 256) bhist[b * NBB + blk] = lh[b];
}

// ============ Pass 2a: scan each bucket's 256 block-counts ============
__global__ __launch_bounds__(256) void k_scanH(const int* __restrict__ bhist,
                                               int* __restrict__ boffB, int* __restrict__ btot)
{
    __shared__ int sh[256];
    const int t = threadIdx.x;
    const int b = blockIdx.x;
    const int v = bhist[b * NBB + t];
    sh[t] = v;
    __syncthreads();
    #pragma unroll
    for (int off = 1; off < 256; off <<= 1) {
        const int u = (t >= off) ? sh[t - off] : 0;
        __syncthreads();
        sh[t] += u;
        __syncthreads();
    }
    boffB[b * NBB + t] = sh[t] - v;
    if (t == 255) btot[b] = sh[255];
}

// ============ Pass 2b: scan bucket totals -> bucket start offsets ============
__global__ __launch_bounds__(1024) void k_scanH2(const int* __restrict__ btot,
                                                 int* __restrict__ bstart)
{
    __shared__ int sh[1024];
    const int t = threadIdx.x;
    const int v = (t < NBUCK) ? btot[t] : 0;
    sh[t] = v;
    __syncthreads();
    #pragma unroll
    for (int off = 1; off < 1024; off <<= 1) {
        const int u = (t >= off) ? sh[t - off] : 0;
        __syncthreads();
        sh[t] += u;
        __syncthreads();
    }
    if (t < NBUCK) bstart[t] = sh[t] - v;
    if (t == NBUCK - 1) bstart[NBUCK] = sh[t];
}

// ============ Pass 3: scatter edges into bucket-contiguous packed pairs ============
// pairsP[pos] = (dst % BUCK_W) << 17 | src
__global__ __launch_bounds__(256) void k_scat(const int* __restrict__ ei,
                                              const int* __restrict__ boffB,
                                              const int* __restrict__ bstart,
                                              int* __restrict__ pairsP)
{
    __shared__ int lcur[NBUCK];
    const int t = threadIdx.x;
    const int blk = blockIdx.x;
    for (int b = t; b < NBUCK; b += 256) lcur[b] = bstart[b] + boffB[b * NBB + blk];
    __syncthreads();
    const int base = blk * CHUNK;
    for (int i = t; i < CHUNK; i += 256) {
        const int src = ei[base + i];
        const int dst = ei[N_EDGES + base + i];
        const int b = dst / BUCK_W;
        const int pos = atomicAdd(&lcur[b], 1);
        pairsP[pos] = ((dst - b * BUCK_W) << 17) | src;
    }
}

// ============ Weight fusion: W' = W1b @ W1a  [32][256], b' = W1b@b1a + b1b ============
__global__ __launch_bounds__(256) void k_wfuse(
    const float* __restrict__ w1a_w, const float* __restrict__ w1a_b,
    const float* __restrict__ w1b_w, const float* __restrict__ w1b_b,
    float* __restrict__ wp, float* __restrict__ bp)
{
    __shared__ float wb_s[32][32];
    __shared__ float ba_s[32];
    const int t = threadIdx.x;
    for (int i = t; i < 1024; i += 256) wb_s[i >> 5][i & 31] = w1b_w[i];
    if (t < 32) ba_s[t] = w1a_b[t];
    __syncthreads();
    const int k = t;                       // 0..255
    for (int o = 0; o < 32; ++o) {
        float s = 0.f;
        #pragma unroll 8
        for (int c = 0; c < 32; ++c) s += wb_s[o][c] * w1a_w[c * 256 + k];
        wp[o * 256 + k] = s;
    }
    if (t < 32) {
        float s = 0.f;
        for (int c = 0; c < 32; ++c) s += wb_s[t][c] * ba_s[c];
        bp[t] = s + w1b_b[t];
    }
}

// ============ Layer 1 GEMM (single pass over x, bf16-packed weight tiles):
// h1b = bf16(x@W1a^T + b1a)  AND  out1 = x@W'^T + b'.
// LDS: 2 x uint[256][17] = 34.8 KB -> 4 blocks/CU (16 waves).
__global__ __launch_bounds__(256, 4) void k1_gemm(
    const float* __restrict__ x,
    const float* __restrict__ w1a_w, const float* __restrict__ w1a_b,
    const float* __restrict__ wp, const float* __restrict__ bp,
    ushort_t* __restrict__ h1b, float* __restrict__ out1)
{
    __shared__ uint_t wsA[256][17];   // packed bf16 pairs of W1a^T (outputs 2j,2j+1)
    __shared__ uint_t wsB[256][17];   // packed bf16 pairs of W'^T

    const int t = threadIdx.x;
    const int node0 = (int)blockIdx.x * 256;

    for (int i = t; i < 256 * 16; i += 256) {
        const int k = i >> 4, j = i & 15;
        wsA[k][j] = (uint_t)f2bf(w1a_w[(2 * j) * 256 + k])
                  | ((uint_t)f2bf(w1a_w[(2 * j + 1) * 256 + k]) << 16);
        wsB[k][j] = (uint_t)f2bf(wp[(2 * j) * 256 + k])
                  | ((uint_t)f2bf(wp[(2 * j + 1) * 256 + k]) << 16);
    }
    __syncthreads();

    const int og = t & 3;
    const int ng = t >> 2;
    const int o0 = og * 8;
    const int j0 = og * 4;               // uint columns j0..j0+3 -> outputs o0..o0+7

    int nid[4]; bool val[4];
    #pragma unroll
    for (int j = 0; j < 4; ++j) { nid[j] = node0 + ng * 4 + j; val[j] = nid[j] < N_NODES; }

    float biasA[8], biasB[8];
    #pragma unroll
    for (int o = 0; o < 8; ++o) { biasA[o] = w1a_b[o0 + o]; biasB[o] = bp[o0 + o]; }

    float acc[4][8] = {};    // h accumulators
    float acc2[4][8] = {};   // out1 accumulators
    for (int kc = 0; kc < 64; ++kc) {
        float4 x4[4];
        #pragma unroll
        for (int j = 0; j < 4; ++j) {
            x4[j] = val[j] ? ((const float4*)(x + (size_t)nid[j] * IN_F))[kc]
                           : make_float4(0.f, 0.f, 0.f, 0.f);
        }
        #pragma unroll
        for (int u = 0; u < 4; ++u) {
            const int k = kc * 4 + u;
            const uint4 wa = *(const uint4*)&wsA[k][j0];
            const uint4 wb = *(const uint4*)&wsB[k][j0];
            const float a0 = bf_lo(wa.x), a1 = bf_hi(wa.x);
            const float a2 = bf_lo(wa.y), a3 = bf_hi(wa.y);
            const float a4 = bf_lo(wa.z), a5 = bf_hi(wa.z);
            const float a6 = bf_lo(wa.w), a7 = bf_hi(wa.w);
            const float b0 = bf_lo(wb.x), b1 = bf_hi(wb.x);
            const float b2 = bf_lo(wb.y), b3 = bf_hi(wb.y);
            const float b4 = bf_lo(wb.z), b5 = bf_hi(wb.z);
            const float b6 = bf_lo(wb.w), b7 = bf_hi(wb.w);
            #pragma unroll
            for (int j = 0; j < 4; ++j) {
                const float xv = (u == 0) ? x4[j].x : (u == 1) ? x4[j].y
                               : (u == 2) ? x4[j].z : x4[j].w;
                acc[j][0]  += xv * a0; acc[j][1]  += xv * a1;
                acc[j][2]  += xv * a2; acc[j][3]  += xv * a3;
                acc[j][4]  += xv * a4; acc[j][5]  += xv * a5;
                acc[j][6]  += xv * a6; acc[j][7]  += xv * a7;
                acc2[j][0] += xv * b0; acc2[j][1] += xv * b1;
                acc2[j][2] += xv * b2; acc2[j][3] += xv * b3;
                acc2[j][4] += xv * b4; acc2[j][5] += xv * b5;
                acc2[j][6] += xv * b6; acc2[j][7] += xv * b7;
            }
        }
    }

    #pragma unroll
    for (int j = 0; j < 4; ++j) {
        if (!val[j]) continue;
        uint4 pk;
        pk.x = (uint_t)f2bf(acc[j][0] + biasA[0]) | ((uint_t)f2bf(acc[j][1] + biasA[1]) << 16);
        pk.y = (uint_t)f2bf(acc[j][2] + biasA[2]) | ((uint_t)f2bf(acc[j][3] + biasA[3]) << 16);
        pk.z = (uint_t)f2bf(acc[j][4] + biasA[4]) | ((uint_t)f2bf(acc[j][5] + biasA[5]) << 16);
        pk.w = (uint_t)f2bf(acc[j][6] + biasA[6]) | ((uint_t)f2bf(acc[j][7] + biasA[7]) << 16);
        *(uint4*)(h1b + (size_t)nid[j] * HID + o0) = pk;
        float* dst = out1 + (size_t)nid[j] * HID + o0;
        *(float4*)dst       = make_float4(acc2[j][0] + biasB[0], acc2[j][1] + biasB[1],
                                          acc2[j][2] + biasB[2], acc2[j][3] + biasB[3]);
        *(float4*)(dst + 4) = make_float4(acc2[j][4] + biasB[4], acc2[j][5] + biasB[5],
                                          acc2[j][6] + biasB[6], acc2[j][7] + biasB[7]);
    }
}

// ============ Aggregate layer 1: in-LDS counting sort, register accumulate ============
__global__ __launch_bounds__(256) void k_agg32(const int* __restrict__ bstart,
                                               const int* __restrict__ pairsP,
                                               const ushort_t* __restrict__ h1b,
                                               float* __restrict__ out1)
{
    __shared__ int cnt[128];
    __shared__ int off[129];
    __shared__ int srt[MAXE];
    const int t = threadIdx.x;
    const int b = blockIdx.x;
    const int c = t & 31;
    const int grp = t >> 5;                 // 8 groups of 32 lanes

    const int e0g = bstart[b];
    const int e1g = bstart[b + 1];

    for (int ch0 = e0g; ch0 < e1g; ch0 += MAXE) {
        const int ce = (ch0 + MAXE < e1g) ? (ch0 + MAXE) : e1g;
        const int cn = ce - ch0;

        if (t < 128) cnt[t] = 0;
        __syncthreads();
        for (int i = t; i < cn; i += 256)
            atomicAdd(&cnt[pairsP[ch0 + i] >> 17], 1);
        __syncthreads();
        {
            int v = (t < 128) ? cnt[t] : 0;
            if (t < 128) off[t] = v;
            __syncthreads();
            #pragma unroll
            for (int o = 1; o < 128; o <<= 1) {
                int u = 0;
                if (t < 128 && t >= o) u = off[t - o];
                __syncthreads();
                if (t < 128) off[t] += u;
                __syncthreads();
            }
            if (t < 128) {
                const int inc = off[t];
                off[t] = inc - v;
                cnt[t] = inc - v;
                if (t == 127) off[128] = inc;
            }
        }
        __syncthreads();
        for (int i = t; i < cn; i += 256) {
            const int p = pairsP[ch0 + i];
            const int pos = atomicAdd(&cnt[p >> 17], 1);
            srt[pos] = p & 0x1FFFF;
        }
        __syncthreads();
        for (int n = grp; n < BUCK_W; n += 8) {
            const int e0 = off[n];
            const int e1 = off[n + 1];
            float acc = 0.f, acc2 = 0.f;
            int e = e0;
            for (; e + 1 < e1; e += 2) {
                const int s0 = srt[e];
                const int s1 = srt[e + 1];
                const float v0 = bf2f(h1b[(size_t)s0 * HID + c]);
                const float v1 = bf2f(h1b[(size_t)s1 * HID + c]);
                acc += v0; acc2 += v1;
            }
            if (e < e1) acc += bf2f(h1b[(size_t)srt[e] * HID + c]);
            acc += acc2;
            out1[((size_t)b * BUCK_W + n) * HID + c] += acc;
        }
        __syncthreads();
    }
}

// ============ Layer 2 dense ============
__global__ __launch_bounds__(256) void k3_layer2_dense(
    const float* __restrict__ out1,
    const float* __restrict__ w2a_w, const float* __restrict__ w2a_b,
    const float* __restrict__ w2b_w, const float* __restrict__ w2b_b,
    ushort_t* __restrict__ h2b, float* __restrict__ out2)
{
    __shared__ float rs[64][33];
    __shared__ float h2s[64][17];
    __shared__ float wa[16][33];
    __shared__ float wb[16][17];

    const int t = threadIdx.x;
    const int node0 = blockIdx.x * 64;
    const int nrem = N_NODES - node0;

    for (int i = t; i < 16 * 32; i += 256)
        wa[i >> 5][i & 31] = w2a_w[i];
    if (t < 16 * 16) wb[t >> 4][t & 15] = w2b_w[t];
    for (int i = t; i < 64 * 32; i += 256) {
        int r = i >> 5, c = i & 31;
        float v = 0.f;
        if (r < nrem) v = out1[(size_t)(node0 + r) * HID + c];
        rs[r][c] = fmaxf(v, 0.f);
    }
    __syncthreads();

    const int o = t & 15;
    const int g = t >> 4;

    const float ba = w2a_b[o];
    float acc[4] = {};
    for (int c = 0; c < 32; ++c) {
        const float w = wa[o][c];
        #pragma unroll
        for (int j = 0; j < 4; ++j) acc[j] += rs[g * 4 + j][c] * w;
    }
    #pragma unroll
    for (int j = 0; j < 4; ++j) {
        const int ln = g * 4 + j;
        const float v = acc[j] + ba;
        h2s[ln][o] = v;
        if (ln < nrem) h2b[(size_t)(node0 + ln) * OUTC + o] = f2bf(v);
    }
    __syncthreads();

    const float bbv = w2b_b[o];
    float f[4] = {};
    for (int c = 0; c < 16; ++c) {
        const float w = wb[o][c];
        #pragma unroll
        for (int j = 0; j < 4; ++j) f[j] += h2s[g * 4 + j][c] * w;
    }
    #pragma unroll
    for (int j = 0; j < 4; ++j) {
        const int ln = g * 4 + j;
        if (ln < nrem) out2[(size_t)(node0 + ln) * OUTC + o] = f[j] + bbv;
    }
}

// ============ Aggregate layer 2 (sorted, register acc) + fused log_softmax ============
__global__ __launch_bounds__(256) void k_agg16_sm(const int* __restrict__ bstart,
                                                  const int* __restrict__ pairsP,
                                                  const ushort_t* __restrict__ h2b,
                                                  float* __restrict__ out2)
{
    __shared__ int cnt[128];
    __shared__ int off[129];
    __shared__ int srt[MAXE];
    const int t = threadIdx.x;
    const int b = blockIdx.x;
    const int c = t & 15;
    const int grp = t >> 4;                 // 16 groups of 16 lanes

    const int e0g = bstart[b];
    const int e1g = bstart[b + 1];

    for (int ch0 = e0g; ch0 < e1g; ch0 += MAXE) {
        const int ce = (ch0 + MAXE < e1g) ? (ch0 + MAXE) : e1g;
        const int cn = ce - ch0;
        const bool last = (ce == e1g);

        if (t < 128) cnt[t] = 0;
        __syncthreads();
        for (int i = t; i < cn; i += 256)
            atomicAdd(&cnt[pairsP[ch0 + i] >> 17], 1);
        __syncthreads();
        {
            int v = (t < 128) ? cnt[t] : 0;
            if (t < 128) off[t] = v;
            __syncthreads();
            #pragma unroll
            for (int o = 1; o < 128; o <<= 1) {
                int u = 0;
                if (t < 128 && t >= o) u = off[t - o];
                __syncthreads();
                if (t < 128) off[t] += u;
                __syncthreads();
            }
            if (t < 128) {
                const int inc = off[t];
                off[t] = inc - v;
                cnt[t] = inc - v;
                if (t == 127) off[128] = inc;
            }
        }
        __syncthreads();
        for (int i = t; i < cn; i += 256) {
            const int p = pairsP[ch0 + i];
            const int pos = atomicAdd(&cnt[p >> 17], 1);
            srt[pos] = p & 0x1FFFF;
        }
        __syncthreads();

        for (int n = grp; n < BUCK_W; n += 16) {
            const int e0 = off[n];
            const int e1 = off[n + 1];
            float acc = 0.f, acc2 = 0.f;
            int e = e0;
            for (; e + 1 < e1; e += 2) {
                const int s0 = srt[e];
                const int s1 = srt[e + 1];
                const float v0 = bf2f(h2b[(size_t)s0 * OUTC + c]);
                const float v1 = bf2f(h2b[(size_t)s1 * OUTC + c]);
                acc += v0; acc2 += v1;
            }
            if (e < e1) acc += bf2f(h2b[(size_t)srt[e] * OUTC + c]);
            acc += acc2;

            const size_t oidx = ((size_t)b * BUCK_W + n) * OUTC + c;
            if (!last) {
                out2[oidx] += acc;
            } else {
                const float val = out2[oidx] + acc;
                float m = val;
                #pragma unroll
                for (int o = 8; o > 0; o >>= 1)
                    m = fmaxf(m, __shfl_xor(m, o, 16));
                float s = expf(val - m);
                #pragma unroll
                for (int o = 8; o > 0; o >>= 1)
                    s += __shfl_xor(s, o, 16);
                const float lse = m + logf(s);
                out2[oidx] = val - lse;
            }
        }
        __syncthreads();
    }
}

extern "C" void kernel_launch(void* const* d_in, const int* in_sizes, int n_in,
                              void* d_out, int out_size, void* d_ws, size_t ws_size,
                              hipStream_t stream)
{
    const float* x      = (const float*)d_in[0];
    const float* w1a_w  = (const float*)d_in[1];
    const float* w1a_b  = (const float*)d_in[2];
    const float* w1b_w  = (const float*)d_in[3];
    const float* w1b_b  = (const float*)d_in[4];
    const float* w2a_w  = (const float*)d_in[5];
    const float* w2a_b  = (const float*)d_in[6];
    const float* w2b_w  = (const float*)d_in[7];
    const float* w2b_b  = (const float*)d_in[8];
    const int*   ei     = (const int*)d_in[9];
    float* out = (float*)d_out;

    // workspace (~31 MB)
    float*    out1   = (float*)d_ws;                              // 12.8 MB
    ushort_t* h1b    = (ushort_t*)(out1 + (size_t)N_NODES * HID); // 6.4 MB
    ushort_t* h2b    = h1b + (size_t)N_NODES * HID;               // 3.2 MB
    int*      pairsP = (int*)(h2b + (size_t)N_NODES * OUTC);      // 6.4 MB
    int*      bhist  = pairsP + N_EDGES;                          // 1 MB
    int*      boffB  = bhist + NBUCK * NBB;                       // 1 MB
    int*      btot   = boffB + NBUCK * NBB;                       // 1000
    int*      bstart = btot + NBUCK;                              // 1001
    float*    wp     = (float*)(bstart + NBUCK + 1);              // 32*256 f32
    float*    bp     = wp + 32 * 256;                             // 32 f32

    k_cnt   <<<NBB, 256, 0, stream>>>(ei, bhist);
    k_scanH <<<NBUCK, 256, 0, stream>>>(bhist, boffB, btot);
    k_scanH2<<<1, 1024, 0, stream>>>(btot, bstart);
    k_scat  <<<NBB, 256, 0, stream>>>(ei, boffB, bstart, pairsP);
    k_wfuse <<<1, 256, 0, stream>>>(w1a_w, w1a_b, w1b_w, w1b_b, wp, bp);

    k1_gemm<<<(N_NODES + 255) / 256, 256, 0, stream>>>(x, w1a_w, w1a_b, wp, bp, h1b, out1);
    k_agg32<<<NBUCK, 256, 0, stream>>>(bstart, pairsP, h1b, out1);
    k3_layer2_dense<<<(N_NODES + 63) / 64, 256, 0, stream>>>(out1, w2a_w, w2a_b, w2b_w, w2b_b, h2b, out);
    k_agg16_sm<<<NBUCK, 256, 0, stream>>>(bstart, pairsP, h2b, out);
}

// Round 14
// 262.621 us; speedup vs baseline: 1.9197x; 1.9197x over previous
//
#include <hip/hip_runtime.h>
#include <hip/hip_bf16.h>
#include <math.h>

#define N_NODES 100000
#define N_EDGES 1600000
#define IN_F 256
#define HID 32
#define OUTC 16
#define NBUCK 1000
#define BUCK_W 100     // NBUCK * BUCK_W == N_NODES
#define NBB 256        // partition blocks
#define CHUNK 6250     // N_EDGES / NBB
#define MAXE 4096      // per-chunk edge capacity in LDS

typedef unsigned short ushort_t;
typedef unsigned int uint_t;

__device__ inline ushort_t f2bf(float f) {
    union { float f; uint_t u; } v; v.f = f;
    uint_t r = v.u + 0x7fff + ((v.u >> 16) & 1);   // round-to-nearest-even
    return (ushort_t)(r >> 16);
}
__device__ inline float bf2f(ushort_t h) {
    union { uint_t u; float f; } v; v.u = (uint_t)h << 16;
    return v.f;
}
__device__ inline float bf_lo(uint_t d) {
    union { uint_t u; float f; } v; v.u = d << 16;
    return v.f;
}
__device__ inline float bf_hi(uint_t d) {
    union { uint_t u; float f; } v; v.u = d & 0xFFFF0000u;
    return v.f;
}

// ============ Pass 1: per-block bucket histogram (LDS only) ============
__global__ __launch_bounds__(256) void k_cnt(const int* __restrict__ ei, int* __restrict__ bhist)
{
    __shared__ int lh[NBUCK];
    const int t = threadIdx.x;
    const int blk = blockIdx.x;
    for (int b = t; b < NBUCK; b += 256) lh[b] = 0;
    __syncthreads();
    const int base = blk * CHUNK;
    for (int i = t; i < CHUNK; i += 256) {
        const int dst = ei[N_EDGES + base + i];
        atomicAdd(&lh[dst / BUCK_W], 1);
    }
    __syncthreads();
    for (int b = t; b < NBUCK; b += 256) bhist[b * NBB + blk] = lh[b];
}

// ============ Pass 2a: scan each bucket's 256 block-counts ============
__global__ __launch_bounds__(256) void k_scanH(const int* __restrict__ bhist,
                                               int* __restrict__ boffB, int* __restrict__ btot)
{
    __shared__ int sh[256];
    const int t = threadIdx.x;
    const int b = blockIdx.x;
    const int v = bhist[b * NBB + t];
    sh[t] = v;
    __syncthreads();
    #pragma unroll
    for (int off = 1; off < 256; off <<= 1) {
        const int u = (t >= off) ? sh[t - off] : 0;
        __syncthreads();
        sh[t] += u;
        __syncthreads();
    }
    boffB[b * NBB + t] = sh[t] - v;
    if (t == 255) btot[b] = sh[255];
}

// ============ Pass 2b: scan bucket totals -> bucket start offsets ============
__global__ __launch_bounds__(1024) void k_scanH2(const int* __restrict__ btot,
                                                 int* __restrict__ bstart)
{
    __shared__ int sh[1024];
    const int t = threadIdx.x;
    const int v = (t < NBUCK) ? btot[t] : 0;
    sh[t] = v;
    __syncthreads();
    #pragma unroll
    for (int off = 1; off < 1024; off <<= 1) {
        const int u = (t >= off) ? sh[t - off] : 0;
        __syncthreads();
        sh[t] += u;
        __syncthreads();
    }
    if (t < NBUCK) bstart[t] = sh[t] - v;
    if (t == NBUCK - 1) bstart[NBUCK] = sh[t];
}

// ============ Pass 3: scatter edges into bucket-contiguous packed pairs ============
// pairsP[pos] = (dst % BUCK_W) << 17 | src
__global__ __launch_bounds__(256) void k_scat(const int* __restrict__ ei,
                                              const int* __restrict__ boffB,
                                              const int* __restrict__ bstart,
                                              int* __restrict__ pairsP)
{
    __shared__ int lcur[NBUCK];
    const int t = threadIdx.x;
    const int blk = blockIdx.x;
    for (int b = t; b < NBUCK; b += 256) lcur[b] = bstart[b] + boffB[b * NBB + blk];
    __syncthreads();
    const int base = blk * CHUNK;
    for (int i = t; i < CHUNK; i += 256) {
        const int src = ei[base + i];
        const int dst = ei[N_EDGES + base + i];
        const int b = dst / BUCK_W;
        const int pos = atomicAdd(&lcur[b], 1);
        pairsP[pos] = ((dst - b * BUCK_W) << 17) | src;
    }
}

// ============ Layer 1 (2-phase, bf16-packed LDS, conflict-free):
// GEMM1: h = x@W1a^T + b1a (bf16 weights in LDS) -> h1b + hsp
// GEMM2: out1 = h_bf16 @ W1b^T + b1b (transposed f32 W1b tile)
// LDS: 20.5 + 17.4 + 4.6 = 42.5 KB -> 3 blocks/CU; no VGPR cap (no spills).
__global__ __launch_bounds__(256) void k1_gemm(
    const float* __restrict__ x,
    const float* __restrict__ w1a_w, const float* __restrict__ w1a_b,
    const float* __restrict__ w1b_w, const float* __restrict__ w1b_b,
    ushort_t* __restrict__ h1b, float* __restrict__ out1)
{
    __shared__ uint_t wsT[256][20];   // [k][j]: packed bf16 (W1a[2j][k], W1a[2j+1][k]); cols 16..19 pad
    __shared__ uint_t hsp[256][17];   // [node][j]: packed bf16 h pairs
    __shared__ float  wbsT[32][36];   // [c][o]: W1b transposed, padded

    const int t = threadIdx.x;
    const int node0 = (int)blockIdx.x * 256;

    for (int i = t; i < 256 * 16; i += 256) {
        const int k = i >> 4, j = i & 15;
        wsT[k][j] = (uint_t)f2bf(w1a_w[(2 * j) * 256 + k])
                  | ((uint_t)f2bf(w1a_w[(2 * j + 1) * 256 + k]) << 16);
    }
    for (int i = t; i < 32 * 32; i += 256) {
        const int o = i >> 5, c = i & 31;
        wbsT[c][o] = w1b_w[o * 32 + c];
    }
    __syncthreads();

    const int og = t & 3;
    const int ng = t >> 2;
    const int o0 = og * 8;
    const int j0 = og * 4;

    int nid[4]; bool val[4];
    #pragma unroll
    for (int j = 0; j < 4; ++j) { nid[j] = node0 + ng * 4 + j; val[j] = nid[j] < N_NODES; }

    // ---- GEMM1 ----
    float acc[4][8] = {};
    for (int kc = 0; kc < 64; ++kc) {
        float4 x4[4];
        #pragma unroll
        for (int j = 0; j < 4; ++j) {
            x4[j] = val[j] ? ((const float4*)(x + (size_t)nid[j] * IN_F))[kc]
                           : make_float4(0.f, 0.f, 0.f, 0.f);
        }
        #pragma unroll
        for (int u = 0; u < 4; ++u) {
            const int k = kc * 4 + u;
            const uint4 wa = *(const uint4*)&wsT[k][j0];   // aligned: (20k + j0) % 4 == 0
            const float a0 = bf_lo(wa.x), a1 = bf_hi(wa.x);
            const float a2 = bf_lo(wa.y), a3 = bf_hi(wa.y);
            const float a4 = bf_lo(wa.z), a5 = bf_hi(wa.z);
            const float a6 = bf_lo(wa.w), a7 = bf_hi(wa.w);
            #pragma unroll
            for (int j = 0; j < 4; ++j) {
                const float xv = (u == 0) ? x4[j].x : (u == 1) ? x4[j].y
                               : (u == 2) ? x4[j].z : x4[j].w;
                acc[j][0] += xv * a0; acc[j][1] += xv * a1;
                acc[j][2] += xv * a2; acc[j][3] += xv * a3;
                acc[j][4] += xv * a4; acc[j][5] += xv * a5;
                acc[j][6] += xv * a6; acc[j][7] += xv * a7;
            }
        }
    }

    float biasA[8];
    #pragma unroll
    for (int o = 0; o < 8; ++o) biasA[o] = w1a_b[o0 + o];

    #pragma unroll
    for (int j = 0; j < 4; ++j) {
        const int ln = ng * 4 + j;
        uint_t p0 = (uint_t)f2bf(acc[j][0] + biasA[0]) | ((uint_t)f2bf(acc[j][1] + biasA[1]) << 16);
        uint_t p1 = (uint_t)f2bf(acc[j][2] + biasA[2]) | ((uint_t)f2bf(acc[j][3] + biasA[3]) << 16);
        uint_t p2 = (uint_t)f2bf(acc[j][4] + biasA[4]) | ((uint_t)f2bf(acc[j][5] + biasA[5]) << 16);
        uint_t p3 = (uint_t)f2bf(acc[j][6] + biasA[6]) | ((uint_t)f2bf(acc[j][7] + biasA[7]) << 16);
        hsp[ln][j0]     = p0;    // scalar stores: 2-way bank alias max
        hsp[ln][j0 + 1] = p1;
        hsp[ln][j0 + 2] = p2;
        hsp[ln][j0 + 3] = p3;
        if (val[j]) {
            uint4 pk; pk.x = p0; pk.y = p1; pk.z = p2; pk.w = p3;
            *(uint4*)(h1b + (size_t)nid[j] * HID + o0) = pk;
        }
    }
    __syncthreads();

    // ---- GEMM2: f = h_bf16 @ W1b^T + b1b ----
    float f[4][8] = {};
    for (int p = 0; p < 16; ++p) {
        const float4 wl0 = *(const float4*)&wbsT[2 * p][o0];        // channel 2p
        const float4 wl1 = *(const float4*)&wbsT[2 * p][o0 + 4];
        const float4 wh0 = *(const float4*)&wbsT[2 * p + 1][o0];    // channel 2p+1
        const float4 wh1 = *(const float4*)&wbsT[2 * p + 1][o0 + 4];
        #pragma unroll
        for (int j = 0; j < 4; ++j) {
            const uint_t hu = hsp[ng * 4 + j][p];
            const float hl = bf_lo(hu), hh = bf_hi(hu);
            f[j][0] += hl * wl0.x + hh * wh0.x;
            f[j][1] += hl * wl0.y + hh * wh0.y;
            f[j][2] += hl * wl0.z + hh * wh0.z;
            f[j][3] += hl * wl0.w + hh * wh0.w;
            f[j][4] += hl * wl1.x + hh * wh1.x;
            f[j][5] += hl * wl1.y + hh * wh1.y;
            f[j][6] += hl * wl1.z + hh * wh1.z;
            f[j][7] += hl * wl1.w + hh * wh1.w;
        }
    }
    float biasB[8];
    #pragma unroll
    for (int o = 0; o < 8; ++o) biasB[o] = w1b_b[o0 + o];
    #pragma unroll
    for (int j = 0; j < 4; ++j) {
        if (!val[j]) continue;
        float* dst = out1 + (size_t)nid[j] * HID + o0;
        *(float4*)dst       = make_float4(f[j][0] + biasB[0], f[j][1] + biasB[1],
                                          f[j][2] + biasB[2], f[j][3] + biasB[3]);
        *(float4*)(dst + 4) = make_float4(f[j][4] + biasB[4], f[j][5] + biasB[5],
                                          f[j][6] + biasB[6], f[j][7] + biasB[7]);
    }
}

// ============ Aggregate layer 1: in-LDS counting sort, register accumulate ============
__global__ __launch_bounds__(256) void k_agg32(const int* __restrict__ bstart,
                                               const int* __restrict__ pairsP,
                                               const ushort_t* __restrict__ h1b,
                                               float* __restrict__ out1)
{
    __shared__ int cnt[128];
    __shared__ int off[129];
    __shared__ int srt[MAXE];
    const int t = threadIdx.x;
    const int b = blockIdx.x;
    const int c = t & 31;
    const int grp = t >> 5;                 // 8 groups of 32 lanes

    const int e0g = bstart[b];
    const int e1g = bstart[b + 1];

    for (int ch0 = e0g; ch0 < e1g; ch0 += MAXE) {
        const int ce = (ch0 + MAXE < e1g) ? (ch0 + MAXE) : e1g;
        const int cn = ce - ch0;

        if (t < 128) cnt[t] = 0;
        __syncthreads();
        for (int i = t; i < cn; i += 256)
            atomicAdd(&cnt[pairsP[ch0 + i] >> 17], 1);
        __syncthreads();
        {
            int v = (t < 128) ? cnt[t] : 0;
            if (t < 128) off[t] = v;
            __syncthreads();
            #pragma unroll
            for (int o = 1; o < 128; o <<= 1) {
                int u = 0;
                if (t < 128 && t >= o) u = off[t - o];
                __syncthreads();
                if (t < 128) off[t] += u;
                __syncthreads();
            }
            if (t < 128) {
                const int inc = off[t];
                off[t] = inc - v;
                cnt[t] = inc - v;
                if (t == 127) off[128] = inc;
            }
        }
        __syncthreads();
        for (int i = t; i < cn; i += 256) {
            const int p = pairsP[ch0 + i];
            const int pos = atomicAdd(&cnt[p >> 17], 1);
            srt[pos] = p & 0x1FFFF;
        }
        __syncthreads();
        for (int n = grp; n < BUCK_W; n += 8) {
            const int e0 = off[n];
            const int e1 = off[n + 1];
            float acc = 0.f, acc2 = 0.f;
            int e = e0;
            for (; e + 1 < e1; e += 2) {
                const int s0 = srt[e];
                const int s1 = srt[e + 1];
                const float v0 = bf2f(h1b[(size_t)s0 * HID + c]);
                const float v1 = bf2f(h1b[(size_t)s1 * HID + c]);
                acc += v0; acc2 += v1;
            }
            if (e < e1) acc += bf2f(h1b[(size_t)srt[e] * HID + c]);
            acc += acc2;
            out1[((size_t)b * BUCK_W + n) * HID + c] += acc;
        }
        __syncthreads();
    }
}

// ============ Layer 2 dense ============
__global__ __launch_bounds__(256) void k3_layer2_dense(
    const float* __restrict__ out1,
    const float* __restrict__ w2a_w, const float* __restrict__ w2a_b,
    const float* __restrict__ w2b_w, const float* __restrict__ w2b_b,
    ushort_t* __restrict__ h2b, float* __restrict__ out2)
{
    __shared__ float rs[64][33];
    __shared__ float h2s[64][17];
    __shared__ float wa[16][33];
    __shared__ float wb[16][17];

    const int t = threadIdx.x;
    const int node0 = blockIdx.x * 64;
    const int nrem = N_NODES - node0;

    for (int i = t; i < 16 * 32; i += 256)
        wa[i >> 5][i & 31] = w2a_w[i];
    if (t < 16 * 16) wb[t >> 4][t & 15] = w2b_w[t];
    for (int i = t; i < 64 * 32; i += 256) {
        int r = i >> 5, c = i & 31;
        float v = 0.f;
        if (r < nrem) v = out1[(size_t)(node0 + r) * HID + c];
        rs[r][c] = fmaxf(v, 0.f);
    }
    __syncthreads();

    const int o = t & 15;
    const int g = t >> 4;

    const float ba = w2a_b[o];
    float acc[4] = {};
    for (int c = 0; c < 32; ++c) {
        const float w = wa[o][c];
        #pragma unroll
        for (int j = 0; j < 4; ++j) acc[j] += rs[g * 4 + j][c] * w;
    }
    #pragma unroll
    for (int j = 0; j < 4; ++j) {
        const int ln = g * 4 + j;
        const float v = acc[j] + ba;
        h2s[ln][o] = v;
        if (ln < nrem) h2b[(size_t)(node0 + ln) * OUTC + o] = f2bf(v);
    }
    __syncthreads();

    const float bbv = w2b_b[o];
    float f[4] = {};
    for (int c = 0; c < 16; ++c) {
        const float w = wb[o][c];
        #pragma unroll
        for (int j = 0; j < 4; ++j) f[j] += h2s[g * 4 + j][c] * w;
    }
    #pragma unroll
    for (int j = 0; j < 4; ++j) {
        const int ln = g * 4 + j;
        if (ln < nrem) out2[(size_t)(node0 + ln) * OUTC + o] = f[j] + bbv;
    }
}

// ============ Aggregate layer 2 (sorted, register acc) + fused log_softmax ============
__global__ __launch_bounds__(256) void k_agg16_sm(const int* __restrict__ bstart,
                                                  const int* __restrict__ pairsP,
                                                  const ushort_t* __restrict__ h2b,
                                                  float* __restrict__ out2)
{
    __shared__ int cnt[128];
    __shared__ int off[129];
    __shared__ int srt[MAXE];
    const int t = threadIdx.x;
    const int b = blockIdx.x;
    const int c = t & 15;
    const int grp = t >> 4;                 // 16 groups of 16 lanes

    const int e0g = bstart[b];
    const int e1g = bstart[b + 1];

    for (int ch0 = e0g; ch0 < e1g; ch0 += MAXE) {
        const int ce = (ch0 + MAXE < e1g) ? (ch0 + MAXE) : e1g;
        const int cn = ce - ch0;
        const bool last = (ce == e1g);

        if (t < 128) cnt[t] = 0;
        __syncthreads();
        for (int i = t; i < cn; i += 256)
            atomicAdd(&cnt[pairsP[ch0 + i] >> 17], 1);
        __syncthreads();
        {
            int v = (t < 128) ? cnt[t] : 0;
            if (t < 128) off[t] = v;
            __syncthreads();
            #pragma unroll
            for (int o = 1; o < 128; o <<= 1) {
                int u = 0;
                if (t < 128 && t >= o) u = off[t - o];
                __syncthreads();
                if (t < 128) off[t] += u;
                __syncthreads();
            }
            if (t < 128) {
                const int inc = off[t];
                off[t] = inc - v;
                cnt[t] = inc - v;
                if (t == 127) off[128] = inc;
            }
        }
        __syncthreads();
        for (int i = t; i < cn; i += 256) {
            const int p = pairsP[ch0 + i];
            const int pos = atomicAdd(&cnt[p >> 17], 1);
            srt[pos] = p & 0x1FFFF;
        }
        __syncthreads();

        for (int n = grp; n < BUCK_W; n += 16) {
            const int e0 = off[n];
            const int e1 = off[n + 1];
            float acc = 0.f, acc2 = 0.f;
            int e = e0;
            for (; e + 1 < e1; e += 2) {
                const int s0 = srt[e];
                const int s1 = srt[e + 1];
                const float v0 = bf2f(h2b[(size_t)s0 * OUTC + c]);
                const float v1 = bf2f(h2b[(size_t)s1 * OUTC + c]);
                acc += v0; acc2 += v1;
            }
            if (e < e1) acc += bf2f(h2b[(size_t)srt[e] * OUTC + c]);
            acc += acc2;

            const size_t oidx = ((size_t)b * BUCK_W + n) * OUTC + c;
            if (!last) {
                out2[oidx] += acc;
            } else {
                const float val = out2[oidx] + acc;
                float m = val;
                #pragma unroll
                for (int o = 8; o > 0; o >>= 1)
                    m = fmaxf(m, __shfl_xor(m, o, 16));
                float s = expf(val - m);
                #pragma unroll
                for (int o = 8; o > 0; o >>= 1)
                    s += __shfl_xor(s, o, 16);
                const float lse = m + logf(s);
                out2[oidx] = val - lse;
            }
        }
        __syncthreads();
    }
}

extern "C" void kernel_launch(void* const* d_in, const int* in_sizes, int n_in,
                              void* d_out, int out_size, void* d_ws, size_t ws_size,
                              hipStream_t stream)
{
    const float* x      = (const float*)d_in[0];
    const float* w1a_w  = (const float*)d_in[1];
    const float* w1a_b  = (const float*)d_in[2];
    const float* w1b_w  = (const float*)d_in[3];
    const float* w1b_b  = (const float*)d_in[4];
    const float* w2a_w  = (const float*)d_in[5];
    const float* w2a_b  = (const float*)d_in[6];
    const float* w2b_w  = (const float*)d_in[7];
    const float* w2b_b  = (const float*)d_in[8];
    const int*   ei     = (const int*)d_in[9];
    float* out = (float*)d_out;

    // workspace (~31 MB)
    float*    out1   = (float*)d_ws;                              // 12.8 MB
    ushort_t* h1b    = (ushort_t*)(out1 + (size_t)N_NODES * HID); // 6.4 MB
    ushort_t* h2b    = h1b + (size_t)N_NODES * HID;               // 3.2 MB
    int*      pairsP = (int*)(h2b + (size_t)N_NODES * OUTC);      // 6.4 MB
    int*      bhist  = pairsP + N_EDGES;                          // 1 MB
    int*      boffB  = bhist + NBUCK * NBB;                       // 1 MB
    int*      btot   = boffB + NBUCK * NBB;                       // 1000
    int*      bstart = btot + NBUCK;                              // 1001

    k_cnt   <<<NBB, 256, 0, stream>>>(ei, bhist);
    k_scanH <<<NBUCK, 256, 0, stream>>>(bhist, boffB, btot);
    k_scanH2<<<1, 1024, 0, stream>>>(btot, bstart);
    k_scat  <<<NBB, 256, 0, stream>>>(ei, boffB, bstart, pairsP);

    k1_gemm<<<(N_NODES + 255) / 256, 256, 0, stream>>>(x, w1a_w, w1a_b, w1b_w, w1b_b, h1b, out1);
    k_agg32<<<NBUCK, 256, 0, stream>>>(bstart, pairsP, h1b, out1);
    k3_layer2_dense<<<(N_NODES + 63) / 64, 256, 0, stream>>>(out1, w2a_w, w2a_b, w2b_w, w2b_b, h2b, out);
    k_agg16_sm<<<NBUCK, 256, 0, stream>>>(bstart, pairsP, h2b, out);
}

// Round 15
// 200.370 us; speedup vs baseline: 2.5161x; 1.3107x over previous
//
#include <hip/hip_runtime.h>
#include <hip/hip_bf16.h>
#include <math.h>

#define N_NODES 100000
#define N_EDGES 1600000
#define IN_F 256
#define HID 32
#define OUTC 16
#define NBUCK 1000
#define BUCK_W 100     // NBUCK * BUCK_W == N_NODES
#define NBB 256        // partition blocks
#define CHUNK 6250     // N_EDGES / NBB
#define MAXE 4096      // per-chunk edge capacity in LDS

typedef unsigned short ushort_t;
typedef unsigned int uint_t;
typedef __attribute__((ext_vector_type(8))) short bf16x8;   // 8 bf16 = 4 VGPR (guide §3)
typedef __attribute__((ext_vector_type(4))) float f32x4;    // MFMA C/D

__device__ inline ushort_t f2bf(float f) {
    union { float f; uint_t u; } v; v.f = f;
    uint_t r = v.u + 0x7fff + ((v.u >> 16) & 1);   // round-to-nearest-even
    return (ushort_t)(r >> 16);
}
__device__ inline float bf2f(ushort_t h) {
    union { uint_t u; float f; } v; v.u = (uint_t)h << 16;
    return v.f;
}

// ============ Pass 1: per-block bucket histogram (LDS only) ============
__global__ __launch_bounds__(256) void k_cnt(const int* __restrict__ ei, int* __restrict__ bhist)
{
    __shared__ int lh[NBUCK];
    const int t = threadIdx.x;
    const int blk = blockIdx.x;
    for (int b = t; b < NBUCK; b += 256) lh[b] = 0;
    __syncthreads();
    const int base = blk * CHUNK;
    for (int i = t; i < CHUNK; i += 256) {
        const int dst = ei[N_EDGES + base + i];
        atomicAdd(&lh[dst / BUCK_W], 1);
    }
    __syncthreads();
    for (int b = t; b < NBUCK; b += 256) bhist[b * NBB + blk] = lh[b];
}

// ============ Pass 2a: scan each bucket's 256 block-counts ============
__global__ __launch_bounds__(256) void k_scanH(const int* __restrict__ bhist,
                                               int* __restrict__ boffB, int* __restrict__ btot)
{
    __shared__ int sh[256];
    const int t = threadIdx.x;
    const int b = blockIdx.x;
    const int v = bhist[b * NBB + t];
    sh[t] = v;
    __syncthreads();
    #pragma unroll
    for (int off = 1; off < 256; off <<= 1) {
        const int u = (t >= off) ? sh[t - off] : 0;
        __syncthreads();
        sh[t] += u;
        __syncthreads();
    }
    boffB[b * NBB + t] = sh[t] - v;
    if (t == 255) btot[b] = sh[255];
}

// ============ Pass 2b: scan bucket totals -> bucket start offsets ============
__global__ __launch_bounds__(1024) void k_scanH2(const int* __restrict__ btot,
                                                 int* __restrict__ bstart)
{
    __shared__ int sh[1024];
    const int t = threadIdx.x;
    const int v = (t < NBUCK) ? btot[t] : 0;
    sh[t] = v;
    __syncthreads();
    #pragma unroll
    for (int off = 1; off < 1024; off <<= 1) {
        const int u = (t >= off) ? sh[t - off] : 0;
        __syncthreads();
        sh[t] += u;
        __syncthreads();
    }
    if (t < NBUCK) bstart[t] = sh[t] - v;
    if (t == NBUCK - 1) bstart[NBUCK] = sh[t];
}

// ============ Pass 3: scatter edges into bucket-contiguous packed pairs ============
// pairsP[pos] = (dst % BUCK_W) << 17 | src
__global__ __launch_bounds__(256) void k_scat(const int* __restrict__ ei,
                                              const int* __restrict__ boffB,
                                              const int* __restrict__ bstart,
                                              int* __restrict__ pairsP)
{
    __shared__ int lcur[NBUCK];
    const int t = threadIdx.x;
    const int blk = blockIdx.x;
    for (int b = t; b < NBUCK; b += 256) lcur[b] = bstart[b] + boffB[b * NBB + blk];
    __syncthreads();
    const int base = blk * CHUNK;
    for (int i = t; i < CHUNK; i += 256) {
        const int src = ei[base + i];
        const int dst = ei[N_EDGES + base + i];
        const int b = dst / BUCK_W;
        const int pos = atomicAdd(&lcur[b], 1);
        pairsP[pos] = ((dst - b * BUCK_W) << 17) | src;
    }
}

// ============ Weight fusion + MFMA B-fragment packing ============
// W' = W1b@W1a, b' = W1b@b1a + b1b; then pack W1a (q=0,1) and W' (q=2,3)
// into B-fragment layout for mfma_f32_16x16x32_bf16:
//   fragment elem j of lane l for (q,ks): B[ks*32 + (l>>4)*8 + j][(q&1)*16 + (l&15)]
__global__ __launch_bounds__(256) void k_wfuse(
    const float* __restrict__ w1a_w, const float* __restrict__ w1a_b,
    const float* __restrict__ w1b_w, const float* __restrict__ w1b_b,
    ushort_t* __restrict__ wpack, float* __restrict__ bp)
{
    __shared__ float wps[32][256];   // W' (32 KB)
    __shared__ float wb_s[32][32];
    __shared__ float ba_s[32];
    const int t = threadIdx.x;
    for (int i = t; i < 1024; i += 256) wb_s[i >> 5][i & 31] = w1b_w[i];
    if (t < 32) ba_s[t] = w1a_b[t];
    __syncthreads();
    const int k = t;                       // 0..255
    for (int o = 0; o < 32; ++o) {
        float s = 0.f;
        #pragma unroll 8
        for (int c = 0; c < 32; ++c) s += wb_s[o][c] * w1a_w[c * 256 + k];
        wps[o][k] = s;
    }
    if (t < 32) {
        float s = 0.f;
        for (int c = 0; c < 32; ++c) s += wb_s[t][c] * ba_s[c];
        bp[t] = s + w1b_b[t];
    }
    __syncthreads();
    for (int idx = t; idx < 4 * 8 * 64 * 8; idx += 256) {
        const int j  = idx & 7;
        const int l  = (idx >> 3) & 63;
        const int ks = (idx >> 9) & 7;
        const int q  = idx >> 12;
        const int ncol = ((q & 1) << 4) + (l & 15);
        const int krow = ks * 32 + ((l >> 4) << 3) + j;
        const float v = (q < 2) ? w1a_w[ncol * 256 + krow] : wps[ncol][krow];
        wpack[idx] = f2bf(v);
    }
}

// ============ Layer 1 via MFMA: h1b = bf16(x@W1a^T + b1a), out1 = x@W'^T + b' ====
// Wave = 16 nodes; 4 C-tiles (h lo/hi, out1 lo/hi); zero LDS; fragments from L2.
__global__ __launch_bounds__(256) void k1_mfma(
    const float* __restrict__ x,
    const float* __restrict__ w1a_b, const float* __restrict__ bp,
    const ushort_t* __restrict__ wpack,
    ushort_t* __restrict__ h1b, float* __restrict__ out1)
{
    const int t = threadIdx.x;
    const int lane = t & 63;
    const int wv = t >> 6;
    const int node0 = blockIdx.x * 64 + wv * 16;

    const int arow = lane & 15;          // A row (node within tile)
    const int kq   = lane >> 4;          // k-quadrant (8 elems each)
    int nodeA = node0 + arow;
    if (nodeA >= N_NODES) nodeA = N_NODES - 1;   // clamp; results discarded

    const float* xr = x + (size_t)nodeA * IN_F + kq * 8;
    const bf16x8* wf = (const bf16x8*)wpack;

    f32x4 accA0 = {0.f, 0.f, 0.f, 0.f};
    f32x4 accA1 = {0.f, 0.f, 0.f, 0.f};
    f32x4 accB0 = {0.f, 0.f, 0.f, 0.f};
    f32x4 accB1 = {0.f, 0.f, 0.f, 0.f};

    #pragma unroll
    for (int ks = 0; ks < 8; ++ks) {
        const float4 xlo = *(const float4*)(xr + ks * 32);
        const float4 xhi = *(const float4*)(xr + ks * 32 + 4);
        bf16x8 a;
        a[0] = (short)f2bf(xlo.x); a[1] = (short)f2bf(xlo.y);
        a[2] = (short)f2bf(xlo.z); a[3] = (short)f2bf(xlo.w);
        a[4] = (short)f2bf(xhi.x); a[5] = (short)f2bf(xhi.y);
        a[6] = (short)f2bf(xhi.z); a[7] = (short)f2bf(xhi.w);
        const bf16x8 bA0 = wf[(0 * 8 + ks) * 64 + lane];
        const bf16x8 bA1 = wf[(1 * 8 + ks) * 64 + lane];
        const bf16x8 bB0 = wf[(2 * 8 + ks) * 64 + lane];
        const bf16x8 bB1 = wf[(3 * 8 + ks) * 64 + lane];
        accA0 = __builtin_amdgcn_mfma_f32_16x16x32_bf16(a, bA0, accA0, 0, 0, 0);
        accA1 = __builtin_amdgcn_mfma_f32_16x16x32_bf16(a, bA1, accA1, 0, 0, 0);
        accB0 = __builtin_amdgcn_mfma_f32_16x16x32_bf16(a, bB0, accB0, 0, 0, 0);
        accB1 = __builtin_amdgcn_mfma_f32_16x16x32_bf16(a, bB1, accB1, 0, 0, 0);
    }

    // C/D layout (guide-verified): col = lane&15 (channel), row = (lane>>4)*4 + r (node)
    const int ch = lane & 15;
    const int rbase = (lane >> 4) * 4;
    const float ba0 = w1a_b[ch];
    const float ba1 = w1a_b[ch + 16];
    const float bb0 = bp[ch];
    const float bb1 = bp[ch + 16];

    #pragma unroll
    for (int r = 0; r < 4; ++r) {
        const int node = node0 + rbase + r;
        if (node < N_NODES) {
            h1b[(size_t)node * HID + ch]       = f2bf(accA0[r] + ba0);
            h1b[(size_t)node * HID + ch + 16]  = f2bf(accA1[r] + ba1);
            out1[(size_t)node * HID + ch]      = accB0[r] + bb0;
            out1[(size_t)node * HID + ch + 16] = accB1[r] + bb1;
        }
    }
}

// ============ Aggregate layer 1: in-LDS counting sort, register accumulate ============
__global__ __launch_bounds__(256) void k_agg32(const int* __restrict__ bstart,
                                               const int* __restrict__ pairsP,
                                               const ushort_t* __restrict__ h1b,
                                               float* __restrict__ out1)
{
    __shared__ int cnt[128];
    __shared__ int off[129];
    __shared__ int srt[MAXE];
    const int t = threadIdx.x;
    const int b = blockIdx.x;
    const int c = t & 31;
    const int grp = t >> 5;                 // 8 groups of 32 lanes

    const int e0g = bstart[b];
    const int e1g = bstart[b + 1];

    for (int ch0 = e0g; ch0 < e1g; ch0 += MAXE) {
        const int ce = (ch0 + MAXE < e1g) ? (ch0 + MAXE) : e1g;
        const int cn = ce - ch0;

        if (t < 128) cnt[t] = 0;
        __syncthreads();
        for (int i = t; i < cn; i += 256)
            atomicAdd(&cnt[pairsP[ch0 + i] >> 17], 1);
        __syncthreads();
        {
            int v = (t < 128) ? cnt[t] : 0;
            if (t < 128) off[t] = v;
            __syncthreads();
            #pragma unroll
            for (int o = 1; o < 128; o <<= 1) {
                int u = 0;
                if (t < 128 && t >= o) u = off[t - o];
                __syncthreads();
                if (t < 128) off[t] += u;
                __syncthreads();
            }
            if (t < 128) {
                const int inc = off[t];
                off[t] = inc - v;
                cnt[t] = inc - v;
                if (t == 127) off[128] = inc;
            }
        }
        __syncthreads();
        for (int i = t; i < cn; i += 256) {
            const int p = pairsP[ch0 + i];
            const int pos = atomicAdd(&cnt[p >> 17], 1);
            srt[pos] = p & 0x1FFFF;
        }
        __syncthreads();
        for (int n = grp; n < BUCK_W; n += 8) {
            const int e0 = off[n];
            const int e1 = off[n + 1];
            float acc = 0.f, acc2 = 0.f;
            int e = e0;
            for (; e + 1 < e1; e += 2) {
                const int s0 = srt[e];
                const int s1 = srt[e + 1];
                const float v0 = bf2f(h1b[(size_t)s0 * HID + c]);
                const float v1 = bf2f(h1b[(size_t)s1 * HID + c]);
                acc += v0; acc2 += v1;
            }
            if (e < e1) acc += bf2f(h1b[(size_t)srt[e] * HID + c]);
            acc += acc2;
            out1[((size_t)b * BUCK_W + n) * HID + c] += acc;
        }
        __syncthreads();
    }
}

// ============ Layer 2 dense ============
__global__ __launch_bounds__(256) void k3_layer2_dense(
    const float* __restrict__ out1,
    const float* __restrict__ w2a_w, const float* __restrict__ w2a_b,
    const float* __restrict__ w2b_w, const float* __restrict__ w2b_b,
    ushort_t* __restrict__ h2b, float* __restrict__ out2)
{
    __shared__ float rs[64][33];
    __shared__ float h2s[64][17];
    __shared__ float wa[16][33];
    __shared__ float wb[16][17];

    const int t = threadIdx.x;
    const int node0 = blockIdx.x * 64;
    const int nrem = N_NODES - node0;

    for (int i = t; i < 16 * 32; i += 256)
        wa[i >> 5][i & 31] = w2a_w[i];
    if (t < 16 * 16) wb[t >> 4][t & 15] = w2b_w[t];
    for (int i = t; i < 64 * 32; i += 256) {
        int r = i >> 5, c = i & 31;
        float v = 0.f;
        if (r < nrem) v = out1[(size_t)(node0 + r) * HID + c];
        rs[r][c] = fmaxf(v, 0.f);
    }
    __syncthreads();

    const int o = t & 15;
    const int g = t >> 4;

    const float ba = w2a_b[o];
    float acc[4] = {};
    for (int c = 0; c < 32; ++c) {
        const float w = wa[o][c];
        #pragma unroll
        for (int j = 0; j < 4; ++j) acc[j] += rs[g * 4 + j][c] * w;
    }
    #pragma unroll
    for (int j = 0; j < 4; ++j) {
        const int ln = g * 4 + j;
        const float v = acc[j] + ba;
        h2s[ln][o] = v;
        if (ln < nrem) h2b[(size_t)(node0 + ln) * OUTC + o] = f2bf(v);
    }
    __syncthreads();

    const float bbv = w2b_b[o];
    float f[4] = {};
    for (int c = 0; c < 16; ++c) {
        const float w = wb[o][c];
        #pragma unroll
        for (int j = 0; j < 4; ++j) f[j] += h2s[g * 4 + j][c] * w;
    }
    #pragma unroll
    for (int j = 0; j < 4; ++j) {
        const int ln = g * 4 + j;
        if (ln < nrem) out2[(size_t)(node0 + ln) * OUTC + o] = f[j] + bbv;
    }
}

// ============ Aggregate layer 2 (sorted, register acc) + fused log_softmax ============
__global__ __launch_bounds__(256) void k_agg16_sm(const int* __restrict__ bstart,
                                                  const int* __restrict__ pairsP,
                                                  const ushort_t* __restrict__ h2b,
                                                  float* __restrict__ out2)
{
    __shared__ int cnt[128];
    __shared__ int off[129];
    __shared__ int srt[MAXE];
    const int t = threadIdx.x;
    const int b = blockIdx.x;
    const int c = t & 15;
    const int grp = t >> 4;                 // 16 groups of 16 lanes

    const int e0g = bstart[b];
    const int e1g = bstart[b + 1];

    for (int ch0 = e0g; ch0 < e1g; ch0 += MAXE) {
        const int ce = (ch0 + MAXE < e1g) ? (ch0 + MAXE) : e1g;
        const int cn = ce - ch0;
        const bool last = (ce == e1g);

        if (t < 128) cnt[t] = 0;
        __syncthreads();
        for (int i = t; i < cn; i += 256)
            atomicAdd(&cnt[pairsP[ch0 + i] >> 17], 1);
        __syncthreads();
        {
            int v = (t < 128) ? cnt[t] : 0;
            if (t < 128) off[t] = v;
            __syncthreads();
            #pragma unroll
            for (int o = 1; o < 128; o <<= 1) {
                int u = 0;
                if (t < 128 && t >= o) u = off[t - o];
                __syncthreads();
                if (t < 128) off[t] += u;
                __syncthreads();
            }
            if (t < 128) {
                const int inc = off[t];
                off[t] = inc - v;
                cnt[t] = inc - v;
                if (t == 127) off[128] = inc;
            }
        }
        __syncthreads();
        for (int i = t; i < cn; i += 256) {
            const int p = pairsP[ch0 + i];
            const int pos = atomicAdd(&cnt[p >> 17], 1);
            srt[pos] = p & 0x1FFFF;
        }
        __syncthreads();

        for (int n = grp; n < BUCK_W; n += 16) {
            const int e0 = off[n];
            const int e1 = off[n + 1];
            float acc = 0.f, acc2 = 0.f;
            int e = e0;
            for (; e + 1 < e1; e += 2) {
                const int s0 = srt[e];
                const int s1 = srt[e + 1];
                const float v0 = bf2f(h2b[(size_t)s0 * OUTC + c]);
                const float v1 = bf2f(h2b[(size_t)s1 * OUTC + c]);
                acc += v0; acc2 += v1;
            }
            if (e < e1) acc += bf2f(h2b[(size_t)srt[e] * OUTC + c]);
            acc += acc2;

            const size_t oidx = ((size_t)b * BUCK_W + n) * OUTC + c;
            if (!last) {
                out2[oidx] += acc;
            } else {
                const float val = out2[oidx] + acc;
                float m = val;
                #pragma unroll
                for (int o = 8; o > 0; o >>= 1)
                    m = fmaxf(m, __shfl_xor(m, o, 16));
                float s = expf(val - m);
                #pragma unroll
                for (int o = 8; o > 0; o >>= 1)
                    s += __shfl_xor(s, o, 16);
                const float lse = m + logf(s);
                out2[oidx] = val - lse;
            }
        }
        __syncthreads();
    }
}

extern "C" void kernel_launch(void* const* d_in, const int* in_sizes, int n_in,
                              void* d_out, int out_size, void* d_ws, size_t ws_size,
                              hipStream_t stream)
{
    const float* x      = (const float*)d_in[0];
    const float* w1a_w  = (const float*)d_in[1];
    const float* w1a_b  = (const float*)d_in[2];
    const float* w1b_w  = (const float*)d_in[3];
    const float* w1b_b  = (const float*)d_in[4];
    const float* w2a_w  = (const float*)d_in[5];
    const float* w2a_b  = (const float*)d_in[6];
    const float* w2b_w  = (const float*)d_in[7];
    const float* w2b_b  = (const float*)d_in[8];
    const int*   ei     = (const int*)d_in[9];
    float* out = (float*)d_out;

    // workspace (~31 MB), wpack 16B-aligned
    float*    out1   = (float*)d_ws;                              // 12.8 MB
    ushort_t* h1b    = (ushort_t*)(out1 + (size_t)N_NODES * HID); // 6.4 MB
    ushort_t* h2b    = h1b + (size_t)N_NODES * HID;               // 3.2 MB
    int*      pairsP = (int*)(h2b + (size_t)N_NODES * OUTC);      // 6.4 MB
    ushort_t* wpack  = (ushort_t*)(pairsP + N_EDGES);             // 32 KB (16B-aligned)
    float*    bp     = (float*)(wpack + 4 * 8 * 64 * 8);          // 32 f32
    int*      bhist  = (int*)(bp + 32);                           // 1 MB
    int*      boffB  = bhist + NBUCK * NBB;                       // 1 MB
    int*      btot   = boffB + NBUCK * NBB;                       // 1000
    int*      bstart = btot + NBUCK;                              // 1001

    k_cnt   <<<NBB, 256, 0, stream>>>(ei, bhist);
    k_scanH <<<NBUCK, 256, 0, stream>>>(bhist, boffB, btot);
    k_scanH2<<<1, 1024, 0, stream>>>(btot, bstart);
    k_scat  <<<NBB, 256, 0, stream>>>(ei, boffB, bstart, pairsP);
    k_wfuse <<<1, 256, 0, stream>>>(w1a_w, w1a_b, w1b_w, w1b_b, wpack, bp);

    k1_mfma<<<(N_NODES + 63) / 64, 256, 0, stream>>>(x, w1a_b, bp, wpack, h1b, out1);
    k_agg32<<<NBUCK, 256, 0, stream>>>(bstart, pairsP, h1b, out1);
    k3_layer2_dense<<<(N_NODES + 63) / 64, 256, 0, stream>>>(out1, w2a_w, w2a_b, w2b_w, w2b_b, h2b, out);
    k_agg16_sm<<<NBUCK, 256, 0, stream>>>(bstart, pairsP, h2b, out);
}

// Round 16
// 159.276 us; speedup vs baseline: 3.1653x; 1.2580x over previous
//
#include <hip/hip_runtime.h>
#include <hip/hip_bf16.h>
#include <math.h>

#define N_NODES 100000
#define N_EDGES 1600000
#define IN_F 256
#define HID 32
#define OUTC 16
#define NBUCK 1000
#define BUCK_W 100     // NBUCK * BUCK_W == N_NODES
#define NBB 256        // partition blocks
#define CHUNK 6250     // N_EDGES / NBB
#define MAXE 4096      // per-chunk edge capacity in LDS

typedef unsigned short ushort_t;
typedef unsigned int uint_t;
typedef __attribute__((ext_vector_type(8))) short bf16x8;
typedef __attribute__((ext_vector_type(4))) float f32x4;

__device__ inline ushort_t f2bf(float f) {
    union { float f; uint_t u; } v; v.f = f;
    uint_t r = v.u + 0x7fff + ((v.u >> 16) & 1);
    return (ushort_t)(r >> 16);
}
__device__ inline float bf2f(ushort_t h) {
    union { uint_t u; float f; } v; v.u = (uint_t)h << 16;
    return v.f;
}

// ============ Pass 1: per-block bucket histogram ============
__global__ __launch_bounds__(256) void k_cnt(const int* __restrict__ ei, int* __restrict__ bhist)
{
    __shared__ int lh[NBUCK];
    const int t = threadIdx.x;
    const int blk = blockIdx.x;
    for (int b = t; b < NBUCK; b += 256) lh[b] = 0;
    __syncthreads();
    const int base = blk * CHUNK;
    for (int i = t; i < CHUNK; i += 256) {
        const int dst = ei[N_EDGES + base + i];
        atomicAdd(&lh[dst / BUCK_W], 1);
    }
    __syncthreads();
    for (int b = t; b < NBUCK; b += 256) bhist[b * NBB + blk] = lh[b];
}

// ============ Pass 2a ============
__global__ __launch_bounds__(256) void k_scanH(const int* __restrict__ bhist,
                                               int* __restrict__ boffB, int* __restrict__ btot)
{
    __shared__ int sh[256];
    const int t = threadIdx.x;
    const int b = blockIdx.x;
    const int v = bhist[b * NBB + t];
    sh[t] = v;
    __syncthreads();
    #pragma unroll
    for (int off = 1; off < 256; off <<= 1) {
        const int u = (t >= off) ? sh[t - off] : 0;
        __syncthreads();
        sh[t] += u;
        __syncthreads();
    }
    boffB[b * NBB + t] = sh[t] - v;
    if (t == 255) btot[b] = sh[255];
}

// ============ Pass 2b ============
__global__ __launch_bounds__(1024) void k_scanH2(const int* __restrict__ btot,
                                                 int* __restrict__ bstart)
{
    __shared__ int sh[1024];
    const int t = threadIdx.x;
    const int v = (t < NBUCK) ? btot[t] : 0;
    sh[t] = v;
    __syncthreads();
    #pragma unroll
    for (int off = 1; off < 1024; off <<= 1) {
        const int u = (t >= off) ? sh[t - off] : 0;
        __syncthreads();
        sh[t] += u;
        __syncthreads();
    }
    if (t < NBUCK) bstart[t] = sh[t] - v;
    if (t == NBUCK - 1) bstart[NBUCK] = sh[t];
}

// ============ Pass 3: bucket-grouped packed pairs ============
__global__ __launch_bounds__(256) void k_scat(const int* __restrict__ ei,
                                              const int* __restrict__ boffB,
                                              const int* __restrict__ bstart,
                                              int* __restrict__ pairsP)
{
    __shared__ int lcur[NBUCK];
    const int t = threadIdx.x;
    const int blk = blockIdx.x;
    for (int b = t; b < NBUCK; b += 256) lcur[b] = bstart[b] + boffB[b * NBB + blk];
    __syncthreads();
    const int base = blk * CHUNK;
    for (int i = t; i < CHUNK; i += 256) {
        const int src = ei[base + i];
        const int dst = ei[N_EDGES + base + i];
        const int b = dst / BUCK_W;
        const int pos = atomicAdd(&lcur[b], 1);
        pairsP[pos] = ((dst - b * BUCK_W) << 17) | src;
    }
}

// ============ Weight fusion + MFMA B-fragment packing ============
__global__ __launch_bounds__(256) void k_wfuse(
    const float* __restrict__ w1a_w, const float* __restrict__ w1a_b,
    const float* __restrict__ w1b_w, const float* __restrict__ w1b_b,
    ushort_t* __restrict__ wpack, float* __restrict__ bp)
{
    __shared__ float wps[32][256];
    __shared__ float wb_s[32][32];
    __shared__ float ba_s[32];
    const int t = threadIdx.x;
    for (int i = t; i < 1024; i += 256) wb_s[i >> 5][i & 31] = w1b_w[i];
    if (t < 32) ba_s[t] = w1a_b[t];
    __syncthreads();
    const int k = t;
    for (int o = 0; o < 32; ++o) {
        float s = 0.f;
        #pragma unroll 8
        for (int c = 0; c < 32; ++c) s += wb_s[o][c] * w1a_w[c * 256 + k];
        wps[o][k] = s;
    }
    if (t < 32) {
        float s = 0.f;
        for (int c = 0; c < 32; ++c) s += wb_s[t][c] * ba_s[c];
        bp[t] = s + w1b_b[t];
    }
    __syncthreads();
    for (int idx = t; idx < 4 * 8 * 64 * 8; idx += 256) {
        const int j  = idx & 7;
        const int l  = (idx >> 3) & 63;
        const int ks = (idx >> 9) & 7;
        const int q  = idx >> 12;
        const int ncol = ((q & 1) << 4) + (l & 15);
        const int krow = ks * 32 + ((l >> 4) << 3) + j;
        const float v = (q < 2) ? w1a_w[ncol * 256 + krow] : wps[ncol][krow];
        wpack[idx] = f2bf(v);
    }
}

// ============ Layer 1 via MFMA ============
__global__ __launch_bounds__(256) void k1_mfma(
    const float* __restrict__ x,
    const float* __restrict__ w1a_b, const float* __restrict__ bp,
    const ushort_t* __restrict__ wpack,
    ushort_t* __restrict__ h1b, float* __restrict__ out1)
{
    const int t = threadIdx.x;
    const int lane = t & 63;
    const int wv = t >> 6;
    const int node0 = blockIdx.x * 64 + wv * 16;

    const int arow = lane & 15;
    const int kq   = lane >> 4;
    int nodeA = node0 + arow;
    if (nodeA >= N_NODES) nodeA = N_NODES - 1;

    const float* xr = x + (size_t)nodeA * IN_F + kq * 8;
    const bf16x8* wf = (const bf16x8*)wpack;

    f32x4 accA0 = {0.f, 0.f, 0.f, 0.f};
    f32x4 accA1 = {0.f, 0.f, 0.f, 0.f};
    f32x4 accB0 = {0.f, 0.f, 0.f, 0.f};
    f32x4 accB1 = {0.f, 0.f, 0.f, 0.f};

    #pragma unroll
    for (int ks = 0; ks < 8; ++ks) {
        const float4 xlo = *(const float4*)(xr + ks * 32);
        const float4 xhi = *(const float4*)(xr + ks * 32 + 4);
        bf16x8 a;
        a[0] = (short)f2bf(xlo.x); a[1] = (short)f2bf(xlo.y);
        a[2] = (short)f2bf(xlo.z); a[3] = (short)f2bf(xlo.w);
        a[4] = (short)f2bf(xhi.x); a[5] = (short)f2bf(xhi.y);
        a[6] = (short)f2bf(xhi.z); a[7] = (short)f2bf(xhi.w);
        const bf16x8 bA0 = wf[(0 * 8 + ks) * 64 + lane];
        const bf16x8 bA1 = wf[(1 * 8 + ks) * 64 + lane];
        const bf16x8 bB0 = wf[(2 * 8 + ks) * 64 + lane];
        const bf16x8 bB1 = wf[(3 * 8 + ks) * 64 + lane];
        accA0 = __builtin_amdgcn_mfma_f32_16x16x32_bf16(a, bA0, accA0, 0, 0, 0);
        accA1 = __builtin_amdgcn_mfma_f32_16x16x32_bf16(a, bA1, accA1, 0, 0, 0);
        accB0 = __builtin_amdgcn_mfma_f32_16x16x32_bf16(a, bB0, accB0, 0, 0, 0);
        accB1 = __builtin_amdgcn_mfma_f32_16x16x32_bf16(a, bB1, accB1, 0, 0, 0);
    }

    const int ch = lane & 15;
    const int rbase = (lane >> 4) * 4;
    const float ba0 = w1a_b[ch];
    const float ba1 = w1a_b[ch + 16];
    const float bb0 = bp[ch];
    const float bb1 = bp[ch + 16];

    #pragma unroll
    for (int r = 0; r < 4; ++r) {
        const int node = node0 + rbase + r;
        if (node < N_NODES) {
            h1b[(size_t)node * HID + ch]       = f2bf(accA0[r] + ba0);
            h1b[(size_t)node * HID + ch + 16]  = f2bf(accA1[r] + ba1);
            out1[(size_t)node * HID + ch]      = accB0[r] + bb0;
            out1[(size_t)node * HID + ch + 16] = accB1[r] + bb1;
        }
    }
}

// ============ Aggregate layer 1 (512 threads, 4-deep gather) + persist sort ============
// Writes sorted colg + per-node offg for reuse by k_agg16_sm; writes relu'd out1.
__global__ __launch_bounds__(512) void k_agg32(const int* __restrict__ bstart,
                                               const int* __restrict__ pairsP,
                                               const ushort_t* __restrict__ h1b,
                                               float* __restrict__ out1,
                                               int* __restrict__ colg,
                                               int* __restrict__ offg)
{
    __shared__ int cnt[128];
    __shared__ int off[129];
    __shared__ int srt[MAXE];
    const int t = threadIdx.x;
    const int b = blockIdx.x;
    const int c = t & 31;
    const int grp = t >> 5;                 // 16 groups of 32 lanes

    const int e0g = bstart[b];
    const int e1g = bstart[b + 1];
    const bool single = (e1g - e0g) <= MAXE;

    for (int ch0 = e0g; ch0 < e1g; ch0 += MAXE) {
        const int ce = (ch0 + MAXE < e1g) ? (ch0 + MAXE) : e1g;
        const int cn = ce - ch0;

        if (t < 128) cnt[t] = 0;
        __syncthreads();
        for (int i = t; i < cn; i += 512)
            atomicAdd(&cnt[pairsP[ch0 + i] >> 17], 1);
        __syncthreads();
        {
            int v = (t < 128) ? cnt[t] : 0;
            if (t < 128) off[t] = v;
            __syncthreads();
            #pragma unroll
            for (int o = 1; o < 128; o <<= 1) {
                int u = 0;
                if (t < 128 && t >= o) u = off[t - o];
                __syncthreads();
                if (t < 128) off[t] += u;
                __syncthreads();
            }
            if (t < 128) {
                const int inc = off[t];
                off[t] = inc - v;
                cnt[t] = inc - v;
                if (t == 127) off[128] = inc;
            }
        }
        __syncthreads();
        for (int i = t; i < cn; i += 512) {
            const int p = pairsP[ch0 + i];
            const int pos = atomicAdd(&cnt[p >> 17], 1);
            srt[pos] = p & 0x1FFFF;
        }
        __syncthreads();
        // persist sorted cols (coalesced) + per-node offsets for agg16 reuse
        if (single) {
            for (int i = t; i < cn; i += 512) colg[ch0 + i] = srt[i];
            if (t <= BUCK_W) offg[b * (BUCK_W + 1) + t] = e0g + off[t];
        }
        // gather: 4-deep unrolled, register accumulate
        for (int n = grp; n < BUCK_W; n += 16) {
            const int e0 = off[n];
            const int e1 = off[n + 1];
            float a0 = 0.f, a1 = 0.f, a2 = 0.f, a3 = 0.f;
            int e = e0;
            for (; e + 4 <= e1; e += 4) {
                const int s0 = srt[e];
                const int s1 = srt[e + 1];
                const int s2 = srt[e + 2];
                const int s3 = srt[e + 3];
                a0 += bf2f(h1b[(size_t)s0 * HID + c]);
                a1 += bf2f(h1b[(size_t)s1 * HID + c]);
                a2 += bf2f(h1b[(size_t)s2 * HID + c]);
                a3 += bf2f(h1b[(size_t)s3 * HID + c]);
            }
            for (; e < e1; ++e) a0 += bf2f(h1b[(size_t)srt[e] * HID + c]);
            const float acc = (a0 + a1) + (a2 + a3);
            float* o = &out1[((size_t)b * BUCK_W + n) * HID + c];
            *o = fmaxf(*o + acc, 0.f);      // relu here (idempotent with k3's)
        }
        __syncthreads();
    }
}

// ============ Layer 2 dense ============
__global__ __launch_bounds__(256) void k3_layer2_dense(
    const float* __restrict__ out1,
    const float* __restrict__ w2a_w, const float* __restrict__ w2a_b,
    const float* __restrict__ w2b_w, const float* __restrict__ w2b_b,
    ushort_t* __restrict__ h2b, float* __restrict__ out2)
{
    __shared__ float rs[64][33];
    __shared__ float h2s[64][17];
    __shared__ float wa[16][33];
    __shared__ float wb[16][17];

    const int t = threadIdx.x;
    const int node0 = blockIdx.x * 64;
    const int nrem = N_NODES - node0;

    for (int i = t; i < 16 * 32; i += 256)
        wa[i >> 5][i & 31] = w2a_w[i];
    if (t < 16 * 16) wb[t >> 4][t & 15] = w2b_w[t];
    for (int i = t; i < 64 * 32; i += 256) {
        int r = i >> 5, c = i & 31;
        float v = 0.f;
        if (r < nrem) v = out1[(size_t)(node0 + r) * HID + c];
        rs[r][c] = fmaxf(v, 0.f);
    }
    __syncthreads();

    const int o = t & 15;
    const int g = t >> 4;

    const float ba = w2a_b[o];
    float acc[4] = {};
    for (int c = 0; c < 32; ++c) {
        const float w = wa[o][c];
        #pragma unroll
        for (int j = 0; j < 4; ++j) acc[j] += rs[g * 4 + j][c] * w;
    }
    #pragma unroll
    for (int j = 0; j < 4; ++j) {
        const int ln = g * 4 + j;
        const float v = acc[j] + ba;
        h2s[ln][o] = v;
        if (ln < nrem) h2b[(size_t)(node0 + ln) * OUTC + o] = f2bf(v);
    }
    __syncthreads();

    const float bbv = w2b_b[o];
    float f[4] = {};
    for (int c = 0; c < 16; ++c) {
        const float w = wb[o][c];
        #pragma unroll
        for (int j = 0; j < 4; ++j) f[j] += h2s[g * 4 + j][c] * w;
    }
    #pragma unroll
    for (int j = 0; j < 4; ++j) {
        const int ln = g * 4 + j;
        if (ln < nrem) out2[(size_t)(node0 + ln) * OUTC + o] = f[j] + bbv;
    }
}

// ============ Aggregate layer 2 + log_softmax: reuses agg32's sort (fast path) ============
__global__ __launch_bounds__(512) void k_agg16_sm(const int* __restrict__ bstart,
                                                  const int* __restrict__ pairsP,
                                                  const int* __restrict__ colg,
                                                  const int* __restrict__ offg,
                                                  const ushort_t* __restrict__ h2b,
                                                  float* __restrict__ out2)
{
    const int t = threadIdx.x;
    const int b = blockIdx.x;
    const int c = t & 15;
    const int e0g = bstart[b];
    const int e1g = bstart[b + 1];

    if (e1g - e0g <= MAXE) {
        // fast path: no LDS, no barriers — sorted cols already in colg/offg
        const int grp = t >> 4;             // 32 groups of 16 lanes
        const int ob = b * (BUCK_W + 1);
        for (int n = grp; n < BUCK_W; n += 32) {
            const int e0 = offg[ob + n];
            const int e1 = offg[ob + n + 1];
            float a0 = 0.f, a1 = 0.f, a2 = 0.f, a3 = 0.f;
            int e = e0;
            for (; e + 4 <= e1; e += 4) {
                const int s0 = colg[e];
                const int s1 = colg[e + 1];
                const int s2 = colg[e + 2];
                const int s3 = colg[e + 3];
                a0 += bf2f(h2b[(size_t)s0 * OUTC + c]);
                a1 += bf2f(h2b[(size_t)s1 * OUTC + c]);
                a2 += bf2f(h2b[(size_t)s2 * OUTC + c]);
                a3 += bf2f(h2b[(size_t)s3 * OUTC + c]);
            }
            for (; e < e1; ++e) a0 += bf2f(h2b[(size_t)colg[e] * OUTC + c]);
            const float acc = (a0 + a1) + (a2 + a3);

            const size_t oidx = ((size_t)b * BUCK_W + n) * OUTC + c;
            const float val = out2[oidx] + acc;
            float m = val;
            #pragma unroll
            for (int o = 8; o > 0; o >>= 1)
                m = fmaxf(m, __shfl_xor(m, o, 16));
            float s = expf(val - m);
            #pragma unroll
            for (int o = 8; o > 0; o >>= 1)
                s += __shfl_xor(s, o, 16);
            const float lse = m + logf(s);
            out2[oidx] = val - lse;
        }
        return;
    }

    // fallback: per-chunk counting sort (general correctness)
    __shared__ int cnt[128];
    __shared__ int off[129];
    __shared__ int srt[MAXE];
    const int grp = t >> 4;

    for (int ch0 = e0g; ch0 < e1g; ch0 += MAXE) {
        const int ce = (ch0 + MAXE < e1g) ? (ch0 + MAXE) : e1g;
        const int cn = ce - ch0;
        const bool last = (ce == e1g);

        if (t < 128) cnt[t] = 0;
        __syncthreads();
        for (int i = t; i < cn; i += 512)
            atomicAdd(&cnt[pairsP[ch0 + i] >> 17], 1);
        __syncthreads();
        {
            int v = (t < 128) ? cnt[t] : 0;
            if (t < 128) off[t] = v;
            __syncthreads();
            #pragma unroll
            for (int o = 1; o < 128; o <<= 1) {
                int u = 0;
                if (t < 128 && t >= o) u = off[t - o];
                __syncthreads();
                if (t < 128) off[t] += u;
                __syncthreads();
            }
            if (t < 128) {
                const int inc = off[t];
                off[t] = inc - v;
                cnt[t] = inc - v;
                if (t == 127) off[128] = inc;
            }
        }
        __syncthreads();
        for (int i = t; i < cn; i += 512) {
            const int p = pairsP[ch0 + i];
            const int pos = atomicAdd(&cnt[p >> 17], 1);
            srt[pos] = p & 0x1FFFF;
        }
        __syncthreads();

        for (int n = grp; n < BUCK_W; n += 32) {
            const int e0 = off[n];
            const int e1 = off[n + 1];
            float acc = 0.f, acc2 = 0.f;
            int e = e0;
            for (; e + 1 < e1; e += 2) {
                acc += bf2f(h2b[(size_t)srt[e] * OUTC + c]);
                acc2 += bf2f(h2b[(size_t)srt[e + 1] * OUTC + c]);
            }
            if (e < e1) acc += bf2f(h2b[(size_t)srt[e] * OUTC + c]);
            acc += acc2;

            const size_t oidx = ((size_t)b * BUCK_W + n) * OUTC + c;
            if (!last) {
                out2[oidx] += acc;
            } else {
                const float val = out2[oidx] + acc;
                float m = val;
                #pragma unroll
                for (int o = 8; o > 0; o >>= 1)
                    m = fmaxf(m, __shfl_xor(m, o, 16));
                float s = expf(val - m);
                #pragma unroll
                for (int o = 8; o > 0; o >>= 1)
                    s += __shfl_xor(s, o, 16);
                const float lse = m + logf(s);
                out2[oidx] = val - lse;
            }
        }
        __syncthreads();
    }
}

extern "C" void kernel_launch(void* const* d_in, const int* in_sizes, int n_in,
                              void* d_out, int out_size, void* d_ws, size_t ws_size,
                              hipStream_t stream)
{
    const float* x      = (const float*)d_in[0];
    const float* w1a_w  = (const float*)d_in[1];
    const float* w1a_b  = (const float*)d_in[2];
    const float* w1b_w  = (const float*)d_in[3];
    const float* w1b_b  = (const float*)d_in[4];
    const float* w2a_w  = (const float*)d_in[5];
    const float* w2a_b  = (const float*)d_in[6];
    const float* w2b_w  = (const float*)d_in[7];
    const float* w2b_b  = (const float*)d_in[8];
    const int*   ei     = (const int*)d_in[9];
    float* out = (float*)d_out;

    // workspace (~38 MB)
    float*    out1   = (float*)d_ws;                              // 12.8 MB
    ushort_t* h1b    = (ushort_t*)(out1 + (size_t)N_NODES * HID); // 6.4 MB
    ushort_t* h2b    = h1b + (size_t)N_NODES * HID;               // 3.2 MB
    int*      pairsP = (int*)(h2b + (size_t)N_NODES * OUTC);      // 6.4 MB
    ushort_t* wpack  = (ushort_t*)(pairsP + N_EDGES);             // 32 KB
    float*    bp     = (float*)(wpack + 4 * 8 * 64 * 8);          // 32 f32
    int*      bhist  = (int*)(bp + 32);                           // 1 MB
    int*      boffB  = bhist + NBUCK * NBB;                       // 1 MB
    int*      btot   = boffB + NBUCK * NBB;                       // 1000
    int*      bstart = btot + NBUCK;                              // 1001
    int*      colg   = bstart + NBUCK + 1;                        // 6.4 MB
    int*      offg   = colg + N_EDGES;                            // ~404 KB

    k_cnt   <<<NBB, 256, 0, stream>>>(ei, bhist);
    k_scanH <<<NBUCK, 256, 0, stream>>>(bhist, boffB, btot);
    k_scanH2<<<1, 1024, 0, stream>>>(btot, bstart);
    k_scat  <<<NBB, 256, 0, stream>>>(ei, boffB, bstart, pairsP);
    k_wfuse <<<1, 256, 0, stream>>>(w1a_w, w1a_b, w1b_w, w1b_b, wpack, bp);

    k1_mfma<<<(N_NODES + 63) / 64, 256, 0, stream>>>(x, w1a_b, bp, wpack, h1b, out1);
    k_agg32<<<NBUCK, 512, 0, stream>>>(bstart, pairsP, h1b, out1, colg, offg);
    k3_layer2_dense<<<(N_NODES + 63) / 64, 256, 0, stream>>>(out1, w2a_w, w2a_b, w2b_w, w2b_b, h2b, out);
    k_agg16_sm<<<NBUCK, 512, 0, stream>>>(bstart, pairsP, colg, offg, h2b, out);
}